// Round 11
// baseline (51.477 us; speedup 1.0000x reference)
//
#include <hip/hip_runtime.h>

#define NB 2
#define NP 1024
#define UP 8
#define NG 8192   // NP*UP
#define ND 8192

#define NCD 256           // cd blocks: 8 query-groups (dir|b|qsub) x 32 chunks
#define NRA 64            // reg+arap blocks (16384 threads @ 256/blk)
#define NOV 512           // overlap blocks (4 queries per block, 1 per wave)
#define NTOT (NCD + NRA + NOV)   // 832

// ws layout:
//   [0, 128KB)        : mins (atomicMin targets). memsetAsync'd to 0x7F7F7F7F
//                       (= 2.139e38f, valid +inf-like identity) every call.
//   [128KB, +4)       : completion counter, memset to 0x7F7F7F7F (known init).
//   [132KB, +512*8)   : overlap per-block partials (double)
//   [136KB, +64*6*8)  : reg+arap per-block partials (double x6)
#define WS_MINS(ws)  ((unsigned int*)(ws))
#define WS_CNT(ws)   ((unsigned int*)((char*)(ws) + (128 << 10)))
#define WS_OV(ws)    ((double*)((char*)(ws) + (132 << 10)))
#define WS_RA(ws)    ((double*)((char*)(ws) + (136 << 10)))
#define CNT_INIT 0x7F7F7F7Fu

typedef float v2f __attribute__((ext_vector_type(2)));
union F4 { float4 f; v2f h[2]; };

__device__ __forceinline__ v2f pk_fma(v2f a, v2f b, v2f c) {
  v2f d;
  asm("v_pk_fma_f32 %0, %1, %2, %3" : "=v"(d) : "v"(a), "v"(b), "v"(c));
  return d;
}

__device__ __forceinline__ float wave_reduce_sum(float v) {
  #pragma unroll
  for (int o = 32; o; o >>= 1) v += __shfl_down(v, o);
  return v;
}
__device__ __forceinline__ double wave_reduce_sum_d(double v) {
  #pragma unroll
  for (int o = 32; o; o >>= 1) v += __shfl_down(v, o);
  return v;
}

// ==================== mega kernel: cd | reg+arap | overlap + last-block final ====================
__global__ __launch_bounds__(256, 2) void mega_kernel(const float* __restrict__ gen,
                                                      const float* __restrict__ uv,
                                                      const float* __restrict__ sparse,
                                                      const float* __restrict__ dense,
                                                      void* __restrict__ ws,
                                                      float* __restrict__ out) {
  __shared__ float4 shbuf[1024];   // cd: 256 slots used; overlap: 1024
  __shared__ double aux[32];
  __shared__ double red[4][9];
  __shared__ unsigned last_old;
  int blk = blockIdx.x;
  int tid = threadIdx.x;

  if (blk < NCD) {
    // ===== chamfer: Q=16 queries/thread, 256-target chunk, packed-pair math =====
    // launch_bounds(256,2): VGPR cap 256 (2 waves/SIMD) -> ~170 VGPR state fits, no spill.
    int qg = blk & 7;             // dir(1) | b(1) | qsub(1)
    int chunk = blk >> 3;         // 0..31
    int dir = qg >> 2, b = (qg >> 1) & 1, qsub = qg & 1;
    const float* q; const float* t; unsigned int* mout;
    unsigned int* mins = WS_MINS(ws);
    if (dir == 0) { q = gen + (size_t)b * NG * 3;  t = dense + (size_t)b * ND * 3; mout = mins + b * NG; }
    else          { q = dense + (size_t)b * ND * 3; t = gen + (size_t)b * NG * 3;  mout = mins + NB * NG + b * ND; }

    // stage 256 targets as paired SoA: shbuf[P]={x_e,x_o,y_e,y_o}, shbuf[128+P]={z_e,z_o,w_e,w_o}
    {
      int gi = chunk * 256 + tid;
      float tx = t[gi * 3 + 0], ty = t[gi * 3 + 1], tz = t[gi * 3 + 2];
      float tw = fmaf(tx, tx, fmaf(ty, ty, tz * tz));
      float sx = __shfl_xor(tx, 1), sy = __shfl_xor(ty, 1);
      float sz = __shfl_xor(tz, 1), sw = __shfl_xor(tw, 1);
      int P = tid >> 1;
      if (!(tid & 1)) shbuf[P]       = make_float4(tx, sx, ty, sy);
      else            shbuf[128 + P] = make_float4(sz, tz, sw, tw);
    }

    v2f ax2[16], ay2[16], az2[16];
    float qn[16], m[16];
    #pragma unroll
    for (int qq = 0; qq < 16; ++qq) {
      int qi = qsub * 4096 + qq * 256 + tid;
      float qx = q[qi * 3 + 0], qy = q[qi * 3 + 1], qz = q[qi * 3 + 2];
      qn[qq] = fmaf(qx, qx, fmaf(qy, qy, qz * qz));
      float ax = -2.f * qx, ay = -2.f * qy, az = -2.f * qz;
      ax2[qq] = (v2f){ax, ax}; ay2[qq] = (v2f){ay, ay}; az2[qq] = (v2f){az, az};
      m[qq] = 3.4e38f;
    }
    __syncthreads();

    for (int j = 0; j < 128; ++j) {       // 128 target pairs
      F4 uxy, uzw;
      uxy.f = shbuf[j];                   // broadcast ds_read_b128
      uzw.f = shbuf[128 + j];
      v2f X = uxy.h[0], Y = uxy.h[1], Z = uzw.h[0], W = uzw.h[1];
      #pragma unroll
      for (int qq = 0; qq < 16; ++qq) {
        v2f d = pk_fma(az2[qq], Z, W);    // az*z + |t|^2   (both targets)
        d = pk_fma(ay2[qq], Y, d);
        d = pk_fma(ax2[qq], X, d);
        m[qq] = fminf(fminf(m[qq], d.x), d.y);   // -> v_min3
      }
    }
    #pragma unroll
    for (int qq = 0; qq < 16; ++qq) {
      int qi = qsub * 4096 + qq * 256 + tid;
      atomicMin(&mout[qi], __float_as_uint(m[qq] + qn[qq]));
    }

  } else if (blk < NCD + NRA) {
    // ===== reg + arap: one thread per (group, i) =====
    int lblk = blk - NCD;
    int id = lblk * 256 + tid;          // 0 .. 16383
    int gi = id >> 3, i = id & 7;
    const float* u = uv + (size_t)gi * UP * 2;
    const float* g = gen + (size_t)gi * UP * 3;
    float uxi = u[i * 2], uyi = u[i * 2 + 1];
    float gxi = g[i * 3], gyi = g[i * 3 + 1], gzi = g[i * 3 + 2];

    int b = gi >> 10, p = gi & (NP - 1);
    const float* s = sparse + ((size_t)b * NP + p) * 3;
    float rx = s[0] - gxi, ry = s[1] - gyi, rz = s[2] - gzi;
    float sq = rx * rx + ry * ry + rz * rz;
    float tt = sq - 0.04f;
    float reg = sq * (tt > 0.f ? 1.5f : (tt < 0.f ? 0.5f : 1.0f));

    float d2[UP], gd2[UP];
    #pragma unroll
    for (int j = 0; j < UP; ++j) {
      float dx = uxi - u[j * 2], dy = uyi - u[j * 2 + 1];
      d2[j] = dx * dx + dy * dy;
      float ex = gxi - g[j * 3], ey = gyi - g[j * 3 + 1], ez = gzi - g[j * 3 + 2];
      gd2[j] = ex * ex + ey * ey + ez * ez;
    }
    float suv = 0.f, sg = 0.f, suv2 = 0.f, sg2 = 0.f, suvg = 0.f;
    unsigned mask = 1u << i;            // self has d=0, dropped by top_k's [1:]
    #pragma unroll
    for (int k = 0; k < 4; ++k) {
      float bd = 3.4e38f, bg = 0.f; int bj = 0;
      #pragma unroll
      for (int j = 0; j < UP; ++j) {    // strict < ascending scan == top_k tie-break
        bool skip = (mask & (1u << j)) != 0;
        bool take = !skip && (d2[j] < bd);
        bd = take ? d2[j] : bd;
        bg = take ? gd2[j] : bg;
        bj = take ? j : bj;
      }
      mask |= 1u << bj;
      float uvd = sqrtf(bd + 1e-8f);
      float gd = sqrtf(bg + 1e-8f);
      suv += uvd; sg += gd;
      suv2 += uvd * uvd; sg2 += gd * gd; suvg += uvd * gd;
    }
    float v0 = wave_reduce_sum(reg), v1 = wave_reduce_sum(suv), v2 = wave_reduce_sum(sg);
    float v3 = wave_reduce_sum(suv2), v4 = wave_reduce_sum(sg2), v5 = wave_reduce_sum(suvg);
    int wave = tid >> 6;
    if ((tid & 63) == 0) {
      aux[wave * 6 + 0] = (double)v0; aux[wave * 6 + 1] = (double)v1;
      aux[wave * 6 + 2] = (double)v2; aux[wave * 6 + 3] = (double)v3;
      aux[wave * 6 + 4] = (double)v4; aux[wave * 6 + 5] = (double)v5;
    }
    __syncthreads();
    if (tid < 6) {
      double t6 = aux[tid] + aux[6 + tid] + aux[12 + tid] + aux[18 + tid];
      WS_RA(ws)[lblk * 6 + tid] = t6;
    }

  } else {
    // ===== overlap: one wave per sparse point =====
    int lblk = blk - NCD - NRA;         // 0..511
    int wave = tid >> 6, lane = tid & 63;
    int q = lblk * 4 + wave;            // 0..2047
    int b = q >> 10, p = q & (NP - 1);
    const float* s = sparse + (size_t)b * NP * 3;
    for (int k = tid; k < NP; k += 256)
      shbuf[k] = make_float4(s[k * 3], s[k * 3 + 1], s[k * 3 + 2], 0.f);
    __syncthreads();

    float4 me = shbuf[p];
    float kd[7]; int ki[7];
    #pragma unroll
    for (int k = 0; k < 7; ++k) { kd[k] = 3.4e38f; ki[k] = 0; }
    #pragma unroll
    for (int jj = 0; jj < NP / 64; ++jj) {
      int j = jj * 64 + lane;
      float4 o = shbuf[j];
      float dx = me.x - o.x, dy = me.y - o.y, dz = me.z - o.z;
      float cd = fmaf(dx, dx, fmaf(dy, dy, dz * dz)); int cj = j;
      #pragma unroll
      for (int k = 0; k < 7; ++k) {     // strict < keeps lower idx first on ties
        bool sw = cd < kd[k];
        float td = sw ? kd[k] : cd;  int tj = sw ? ki[k] : cj;
        kd[k] = sw ? cd : kd[k];     ki[k] = sw ? cj : ki[k];
        cd = td; cj = tj;
      }
    }
    // exact global top-7 via 7 pops; key = (dist_bits<<32)|idx
    int nbr[6];
    unsigned long long key = ((unsigned long long)__float_as_uint(kd[0]) << 32) | (unsigned)ki[0];
    #pragma unroll
    for (int t = 0; t < 7; ++t) {
      unsigned long long mm = key;
      #pragma unroll
      for (int o = 32; o; o >>= 1) {
        unsigned long long other = __shfl_xor(mm, o);
        mm = other < mm ? other : mm;
      }
      if (t) nbr[t - 1] = (int)(unsigned)(mm & 0xffffffffu);  // t==0 pops self
      bool win = (key == mm);
      #pragma unroll
      for (int k = 0; k < 6; ++k) { kd[k] = win ? kd[k + 1] : kd[k]; ki[k] = win ? ki[k + 1] : ki[k]; }
      if (win) kd[6] = 3.4e38f;
      key = ((unsigned long long)__float_as_uint(kd[0]) << 32) | (unsigned)ki[0];
    }

    float mval = 3.4e38f;
    if (lane < 48) {
      int n = lane >> 3, k = lane & 7;
      float4 o = shbuf[nbr[n]];
      const float* g = gen + ((size_t)b * NG + (size_t)p * UP + k) * 3;
      float dx = o.x - g[0], dy = o.y - g[1], dz = o.z - g[2];
      mval = fmaf(dx, dx, fmaf(dy, dy, dz * dz));
    }
    #pragma unroll
    for (int o = 1; o < 8; o <<= 1) mval = fminf(mval, __shfl_xor(mval, o));
    float ssum = 0.f;
    #pragma unroll
    for (int n = 0; n < 6; ++n) ssum += __shfl(mval, n * 8);

    if (lane == 0) aux[wave] = (double)ssum;
    __syncthreads();
    if (tid == 0) WS_OV(ws)[lblk] = aux[0] + aux[1] + aux[2] + aux[3];
  }

  // ===== completion ticket; last-arriving block does the final reduce =====
  __syncthreads();
  if (tid == 0) {
    __threadfence();   // release: all our global writes visible before ticket
    last_old = atomicAdd(WS_CNT(ws), 1u);   // device-scope by default
  }
  __syncthreads();
  if (last_old == CNT_INIT + NTOT - 1) {
    __threadfence();   // acquire: see all other blocks' writes
    int wave = tid >> 6, lane = tid & 63;
    const uint4* m4 = (const uint4*)WS_MINS(ws);   // 8192 uint4: [0,4096)=dir0, [4096,8192)=dir1
    const double* ov = WS_OV(ws);
    const double* ra = WS_RA(ws);

    double s[9];
    #pragma unroll
    for (int k = 0; k < 9; ++k) s[k] = 0.0;
    #pragma unroll
    for (int i = 0; i < 16; ++i) {
      uint4 a = m4[tid + i * 256];
      uint4 c = m4[4096 + tid + i * 256];
      s[0] += (double)__uint_as_float(a.x) + (double)__uint_as_float(a.y)
            + (double)__uint_as_float(a.z) + (double)__uint_as_float(a.w);
      s[1] += (double)__uint_as_float(c.x) + (double)__uint_as_float(c.y)
            + (double)__uint_as_float(c.z) + (double)__uint_as_float(c.w);
    }
    s[8] = ov[tid] + ov[256 + tid];
    if (tid < NRA) {
      #pragma unroll
      for (int k = 0; k < 6; ++k) s[2 + k] = ra[tid * 6 + k];
    }
    #pragma unroll
    for (int k = 0; k < 9; ++k) s[k] = wave_reduce_sum_d(s[k]);
    if (lane == 0) {
      #pragma unroll
      for (int k = 0; k < 9; ++k) red[wave][k] = s[k];
    }
    __syncthreads();
    if (tid == 0) {
      double t[9];
      #pragma unroll
      for (int k = 0; k < 9; ++k)
        t[k] = red[0][k] + red[1][k] + red[2][k] + red[3][k];
      double loss_cd = 0.5 * (t[0] + t[1]) / NB;
      double loss_reg = t[2] / NB;
      double scale = t[4] / t[3];                       // sum(g_d)/sum(uv_d)
      double loss_arap = (scale * scale * t[5] + t[6] - 2.0 * scale * t[7]) / NB;
      double loss_ov = t[8] / NB;
      out[0] = (float)(loss_cd + loss_reg + loss_arap + loss_ov);
    }
  }
}

extern "C" void kernel_launch(void* const* d_in, const int* in_sizes, int n_in,
                              void* d_out, int out_size, void* d_ws, size_t ws_size,
                              hipStream_t stream) {
  const float* gen    = (const float*)d_in[0];
  const float* uvc    = (const float*)d_in[2];
  const float* sparse = (const float*)d_in[3];
  const float* dense  = (const float*)d_in[5];
  float* out = (float*)d_out;

  // 0x7F7F7F7F = 2.139e38f: atomicMin identity for mins AND known counter init.
  (void)hipMemsetAsync(d_ws, 0x7F, (128 << 10) + 4, stream);
  mega_kernel<<<NTOT, 256, 0, stream>>>(gen, uvc, sparse, dense, d_ws, out);
}

// Round 12
// 43.012 us; speedup vs baseline: 1.1968x; 1.1968x over previous
//
#include <hip/hip_runtime.h>

#define NB 2
#define NP 1024
#define UP 8
#define NG 8192   // NP*UP
#define ND 8192

#define NCD 256           // cd blocks: 8 query-groups (dir|b|qsub) x 32 chunks
#define NRA 64            // reg+arap blocks (16384 threads @ 256/blk)
#define NOV 512           // overlap blocks (4 queries per block, 1 per wave)
#define NTOT (NCD + NRA + NOV)   // 832

// ws layout:
//   [0, 128KB)        : mins (atomicMin targets). memsetAsync'd to 0x7F7F7F7F
//                       (= 2.139e38f, valid +inf-like identity) every call.
//   [128KB, +4)       : completion counter, memset to 0x7F7F7F7F (known init).
//   [132KB, +512*8)   : overlap per-block partials (double)
//   [136KB, +64*6*8)  : reg+arap per-block partials (double x6)
#define WS_MINS(ws)  ((unsigned int*)(ws))
#define WS_CNT(ws)   ((unsigned int*)((char*)(ws) + (128 << 10)))
#define WS_OV(ws)    ((double*)((char*)(ws) + (132 << 10)))
#define WS_RA(ws)    ((double*)((char*)(ws) + (136 << 10)))
#define CNT_INIT 0x7F7F7F7Fu

typedef float v2f __attribute__((ext_vector_type(2)));
union F4 { float4 f; v2f h[2]; };

__device__ __forceinline__ v2f pk_fma(v2f a, v2f b, v2f c) {
  v2f d;
  asm("v_pk_fma_f32 %0, %1, %2, %3" : "=v"(d) : "v"(a), "v"(b), "v"(c));
  return d;
}

__device__ __forceinline__ float wave_reduce_sum(float v) {
  #pragma unroll
  for (int o = 32; o; o >>= 1) v += __shfl_down(v, o);
  return v;
}
__device__ __forceinline__ double wave_reduce_sum_d(double v) {
  #pragma unroll
  for (int o = 32; o; o >>= 1) v += __shfl_down(v, o);
  return v;
}

// ==================== mega kernel: cd | reg+arap | overlap + last-block final ====================
// amdgpu_waves_per_eu(2,2): min=max=2 waves/EU -> allocator budget 256 VGPR,
// occupancy heuristic disabled -> Q=16 state (~150 VGPR) stays in registers.
// (launch_bounds' 2nd arg alone only sets the MIN -> compiler still targeted
//  7 waves/EU and spilled: R8/R10 showed VGPR_Count=72 + scratch traffic.)
__global__ __launch_bounds__(256)
__attribute__((amdgpu_waves_per_eu(2, 2)))
void mega_kernel(const float* __restrict__ gen,
                 const float* __restrict__ uv,
                 const float* __restrict__ sparse,
                 const float* __restrict__ dense,
                 void* __restrict__ ws,
                 float* __restrict__ out) {
  __shared__ float4 shbuf[1024];   // cd: 256 slots used; overlap: 1024
  __shared__ double aux[32];
  __shared__ double red[4][9];
  __shared__ unsigned last_old;
  int blk = blockIdx.x;
  int tid = threadIdx.x;

  if (blk < NCD) {
    // ===== chamfer: Q=16 queries/thread, 256-target chunk, packed-pair math =====
    int qg = blk & 7;             // dir(1) | b(1) | qsub(1)
    int chunk = blk >> 3;         // 0..31
    int dir = qg >> 2, b = (qg >> 1) & 1, qsub = qg & 1;
    const float* q; const float* t; unsigned int* mout;
    unsigned int* mins = WS_MINS(ws);
    if (dir == 0) { q = gen + (size_t)b * NG * 3;  t = dense + (size_t)b * ND * 3; mout = mins + b * NG; }
    else          { q = dense + (size_t)b * ND * 3; t = gen + (size_t)b * NG * 3;  mout = mins + NB * NG + b * ND; }

    // stage 256 targets as paired SoA: shbuf[P]={x_e,x_o,y_e,y_o}, shbuf[128+P]={z_e,z_o,w_e,w_o}
    {
      int gi = chunk * 256 + tid;
      float tx = t[gi * 3 + 0], ty = t[gi * 3 + 1], tz = t[gi * 3 + 2];
      float tw = fmaf(tx, tx, fmaf(ty, ty, tz * tz));
      float sx = __shfl_xor(tx, 1), sy = __shfl_xor(ty, 1);
      float sz = __shfl_xor(tz, 1), sw = __shfl_xor(tw, 1);
      int P = tid >> 1;
      if (!(tid & 1)) shbuf[P]       = make_float4(tx, sx, ty, sy);
      else            shbuf[128 + P] = make_float4(sz, tz, sw, tw);
    }

    v2f ax2[16], ay2[16], az2[16];
    float qn[16], m[16];
    #pragma unroll
    for (int qq = 0; qq < 16; ++qq) {
      int qi = qsub * 4096 + qq * 256 + tid;
      float qx = q[qi * 3 + 0], qy = q[qi * 3 + 1], qz = q[qi * 3 + 2];
      qn[qq] = fmaf(qx, qx, fmaf(qy, qy, qz * qz));
      float ax = -2.f * qx, ay = -2.f * qy, az = -2.f * qz;
      ax2[qq] = (v2f){ax, ax}; ay2[qq] = (v2f){ay, ay}; az2[qq] = (v2f){az, az};
      m[qq] = 3.4e38f;
    }
    __syncthreads();

    for (int j = 0; j < 128; ++j) {       // 128 target pairs
      F4 uxy, uzw;
      uxy.f = shbuf[j];                   // broadcast ds_read_b128
      uzw.f = shbuf[128 + j];
      v2f X = uxy.h[0], Y = uxy.h[1], Z = uzw.h[0], W = uzw.h[1];
      #pragma unroll
      for (int qq = 0; qq < 16; ++qq) {
        v2f d = pk_fma(az2[qq], Z, W);    // az*z + |t|^2   (both targets)
        d = pk_fma(ay2[qq], Y, d);
        d = pk_fma(ax2[qq], X, d);
        m[qq] = fminf(fminf(m[qq], d.x), d.y);   // -> v_min3
      }
    }
    #pragma unroll
    for (int qq = 0; qq < 16; ++qq) {
      int qi = qsub * 4096 + qq * 256 + tid;
      atomicMin(&mout[qi], __float_as_uint(m[qq] + qn[qq]));
    }

  } else if (blk < NCD + NRA) {
    // ===== reg + arap: one thread per (group, i) =====
    int lblk = blk - NCD;
    int id = lblk * 256 + tid;          // 0 .. 16383
    int gi = id >> 3, i = id & 7;
    const float* u = uv + (size_t)gi * UP * 2;
    const float* g = gen + (size_t)gi * UP * 3;
    float uxi = u[i * 2], uyi = u[i * 2 + 1];
    float gxi = g[i * 3], gyi = g[i * 3 + 1], gzi = g[i * 3 + 2];

    int b = gi >> 10, p = gi & (NP - 1);
    const float* s = sparse + ((size_t)b * NP + p) * 3;
    float rx = s[0] - gxi, ry = s[1] - gyi, rz = s[2] - gzi;
    float sq = rx * rx + ry * ry + rz * rz;
    float tt = sq - 0.04f;
    float reg = sq * (tt > 0.f ? 1.5f : (tt < 0.f ? 0.5f : 1.0f));

    float d2[UP], gd2[UP];
    #pragma unroll
    for (int j = 0; j < UP; ++j) {
      float dx = uxi - u[j * 2], dy = uyi - u[j * 2 + 1];
      d2[j] = dx * dx + dy * dy;
      float ex = gxi - g[j * 3], ey = gyi - g[j * 3 + 1], ez = gzi - g[j * 3 + 2];
      gd2[j] = ex * ex + ey * ey + ez * ez;
    }
    float suv = 0.f, sg = 0.f, suv2 = 0.f, sg2 = 0.f, suvg = 0.f;
    unsigned mask = 1u << i;            // self has d=0, dropped by top_k's [1:]
    #pragma unroll
    for (int k = 0; k < 4; ++k) {
      float bd = 3.4e38f, bg = 0.f; int bj = 0;
      #pragma unroll
      for (int j = 0; j < UP; ++j) {    // strict < ascending scan == top_k tie-break
        bool skip = (mask & (1u << j)) != 0;
        bool take = !skip && (d2[j] < bd);
        bd = take ? d2[j] : bd;
        bg = take ? gd2[j] : bg;
        bj = take ? j : bj;
      }
      mask |= 1u << bj;
      float uvd = sqrtf(bd + 1e-8f);
      float gd = sqrtf(bg + 1e-8f);
      suv += uvd; sg += gd;
      suv2 += uvd * uvd; sg2 += gd * gd; suvg += uvd * gd;
    }
    float v0 = wave_reduce_sum(reg), v1 = wave_reduce_sum(suv), v2 = wave_reduce_sum(sg);
    float v3 = wave_reduce_sum(suv2), v4 = wave_reduce_sum(sg2), v5 = wave_reduce_sum(suvg);
    int wave = tid >> 6;
    if ((tid & 63) == 0) {
      aux[wave * 6 + 0] = (double)v0; aux[wave * 6 + 1] = (double)v1;
      aux[wave * 6 + 2] = (double)v2; aux[wave * 6 + 3] = (double)v3;
      aux[wave * 6 + 4] = (double)v4; aux[wave * 6 + 5] = (double)v5;
    }
    __syncthreads();
    if (tid < 6) {
      double t6 = aux[tid] + aux[6 + tid] + aux[12 + tid] + aux[18 + tid];
      WS_RA(ws)[lblk * 6 + tid] = t6;
    }

  } else {
    // ===== overlap: one wave per sparse point =====
    int lblk = blk - NCD - NRA;         // 0..511
    int wave = tid >> 6, lane = tid & 63;
    int q = lblk * 4 + wave;            // 0..2047
    int b = q >> 10, p = q & (NP - 1);
    const float* s = sparse + (size_t)b * NP * 3;
    for (int k = tid; k < NP; k += 256)
      shbuf[k] = make_float4(s[k * 3], s[k * 3 + 1], s[k * 3 + 2], 0.f);
    __syncthreads();

    float4 me = shbuf[p];
    float kd[7]; int ki[7];
    #pragma unroll
    for (int k = 0; k < 7; ++k) { kd[k] = 3.4e38f; ki[k] = 0; }
    #pragma unroll
    for (int jj = 0; jj < NP / 64; ++jj) {
      int j = jj * 64 + lane;
      float4 o = shbuf[j];
      float dx = me.x - o.x, dy = me.y - o.y, dz = me.z - o.z;
      float cd = fmaf(dx, dx, fmaf(dy, dy, dz * dz)); int cj = j;
      #pragma unroll
      for (int k = 0; k < 7; ++k) {     // strict < keeps lower idx first on ties
        bool sw = cd < kd[k];
        float td = sw ? kd[k] : cd;  int tj = sw ? ki[k] : cj;
        kd[k] = sw ? cd : kd[k];     ki[k] = sw ? cj : ki[k];
        cd = td; cj = tj;
      }
    }
    // exact global top-7 via 7 pops; key = (dist_bits<<32)|idx
    int nbr[6];
    unsigned long long key = ((unsigned long long)__float_as_uint(kd[0]) << 32) | (unsigned)ki[0];
    #pragma unroll
    for (int t = 0; t < 7; ++t) {
      unsigned long long mm = key;
      #pragma unroll
      for (int o = 32; o; o >>= 1) {
        unsigned long long other = __shfl_xor(mm, o);
        mm = other < mm ? other : mm;
      }
      if (t) nbr[t - 1] = (int)(unsigned)(mm & 0xffffffffu);  // t==0 pops self
      bool win = (key == mm);
      #pragma unroll
      for (int k = 0; k < 6; ++k) { kd[k] = win ? kd[k + 1] : kd[k]; ki[k] = win ? ki[k + 1] : ki[k]; }
      if (win) kd[6] = 3.4e38f;
      key = ((unsigned long long)__float_as_uint(kd[0]) << 32) | (unsigned)ki[0];
    }

    float mval = 3.4e38f;
    if (lane < 48) {
      int n = lane >> 3, k = lane & 7;
      float4 o = shbuf[nbr[n]];
      const float* g = gen + ((size_t)b * NG + (size_t)p * UP + k) * 3;
      float dx = o.x - g[0], dy = o.y - g[1], dz = o.z - g[2];
      mval = fmaf(dx, dx, fmaf(dy, dy, dz * dz));
    }
    #pragma unroll
    for (int o = 1; o < 8; o <<= 1) mval = fminf(mval, __shfl_xor(mval, o));
    float ssum = 0.f;
    #pragma unroll
    for (int n = 0; n < 6; ++n) ssum += __shfl(mval, n * 8);

    if (lane == 0) aux[wave] = (double)ssum;
    __syncthreads();
    if (tid == 0) WS_OV(ws)[lblk] = aux[0] + aux[1] + aux[2] + aux[3];
  }

  // ===== completion ticket; last-arriving block does the final reduce =====
  __syncthreads();
  if (tid == 0) {
    __threadfence();   // release: all our global writes visible before ticket
    last_old = atomicAdd(WS_CNT(ws), 1u);   // device-scope by default
  }
  __syncthreads();
  if (last_old == CNT_INIT + NTOT - 1) {
    __threadfence();   // acquire: see all other blocks' writes
    int wave = tid >> 6, lane = tid & 63;
    const uint4* m4 = (const uint4*)WS_MINS(ws);   // 8192 uint4: [0,4096)=dir0, [4096,8192)=dir1
    const double* ov = WS_OV(ws);
    const double* ra = WS_RA(ws);

    double s[9];
    #pragma unroll
    for (int k = 0; k < 9; ++k) s[k] = 0.0;
    #pragma unroll
    for (int i = 0; i < 16; ++i) {
      uint4 a = m4[tid + i * 256];
      uint4 c = m4[4096 + tid + i * 256];
      s[0] += (double)__uint_as_float(a.x) + (double)__uint_as_float(a.y)
            + (double)__uint_as_float(a.z) + (double)__uint_as_float(a.w);
      s[1] += (double)__uint_as_float(c.x) + (double)__uint_as_float(c.y)
            + (double)__uint_as_float(c.z) + (double)__uint_as_float(c.w);
    }
    s[8] = ov[tid] + ov[256 + tid];
    if (tid < NRA) {
      #pragma unroll
      for (int k = 0; k < 6; ++k) s[2 + k] = ra[tid * 6 + k];
    }
    #pragma unroll
    for (int k = 0; k < 9; ++k) s[k] = wave_reduce_sum_d(s[k]);
    if (lane == 0) {
      #pragma unroll
      for (int k = 0; k < 9; ++k) red[wave][k] = s[k];
    }
    __syncthreads();
    if (tid == 0) {
      double t[9];
      #pragma unroll
      for (int k = 0; k < 9; ++k)
        t[k] = red[0][k] + red[1][k] + red[2][k] + red[3][k];
      double loss_cd = 0.5 * (t[0] + t[1]) / NB;
      double loss_reg = t[2] / NB;
      double scale = t[4] / t[3];                       // sum(g_d)/sum(uv_d)
      double loss_arap = (scale * scale * t[5] + t[6] - 2.0 * scale * t[7]) / NB;
      double loss_ov = t[8] / NB;
      out[0] = (float)(loss_cd + loss_reg + loss_arap + loss_ov);
    }
  }
}

extern "C" void kernel_launch(void* const* d_in, const int* in_sizes, int n_in,
                              void* d_out, int out_size, void* d_ws, size_t ws_size,
                              hipStream_t stream) {
  const float* gen    = (const float*)d_in[0];
  const float* uvc    = (const float*)d_in[2];
  const float* sparse = (const float*)d_in[3];
  const float* dense  = (const float*)d_in[5];
  float* out = (float*)d_out;

  // 0x7F7F7F7F = 2.139e38f: atomicMin identity for mins AND known counter init.
  (void)hipMemsetAsync(d_ws, 0x7F, (128 << 10) + 4, stream);
  mega_kernel<<<NTOT, 256, 0, stream>>>(gen, uvc, sparse, dense, d_ws, out);
}